// Round 1
// baseline (770.368 us; speedup 1.0000x reference)
//
#include <hip/hip_runtime.h>
#include <hip/hip_bf16.h>
#include <stdint.h>

typedef _Float16 f16;
typedef _Float16 f16x8 __attribute__((ext_vector_type(8)));
typedef _Float16 f16x4 __attribute__((ext_vector_type(4)));
typedef float f32x4 __attribute__((ext_vector_type(4)));

#define T_TOK 8192
#define H_DIM 1024
#define NHEAD 8
#define V_DIM 2048

// global -> LDS direct load, 16B per lane. LDS dest must be wave-uniform base.
// AS3 truncation trick (CK pattern): low 32 bits of a flat LDS address are the
// LDS byte offset (addrspacecast AS3->flat = {shared_base_hi32, offset}).
__device__ __forceinline__ void gload16(const void* g, void* l) {
  __builtin_amdgcn_global_load_lds(
      (const __attribute__((address_space(1))) void*)(uintptr_t)g,
      (__attribute__((address_space(3))) void*)(unsigned)(uintptr_t)l,
      16, 0, 0);
}

__device__ __forceinline__ float fast_tanh(float x) {
  float xc = fminf(fmaxf(x, -12.f), 12.f);
  float e = __expf(2.f * xc);
  return (e - 1.f) / (e + 1.f);
}

// ---------- fp32 -> fp16 elementwise convert (n4 = n/4 float4 groups) ----------
__global__ __launch_bounds__(256) void k_convert(const float* __restrict__ in,
                                                 f16* __restrict__ out, int n4) {
  int i = blockIdx.x * blockDim.x + threadIdx.x;
  if (i >= n4) return;
  const float4 v = ((const float4*)in)[i];
  f16x4 o;
  o[0] = (f16)v.x; o[1] = (f16)v.y; o[2] = (f16)v.z; o[3] = (f16)v.w;
  ((f16x4*)out)[i] = o;
}

// ---------- fp32 [R][C] -> fp16 [C][R] transpose-convert ----------
__global__ void k_transpose(const float* __restrict__ in, f16* __restrict__ out,
                            int R, int C) {
  __shared__ f16 tile[32][33];
  int c0 = blockIdx.x * 32, r0 = blockIdx.y * 32;
  for (int j = threadIdx.y; j < 32; j += 8)
    tile[j][threadIdx.x] = (f16)in[(size_t)(r0 + j) * C + (c0 + threadIdx.x)];
  __syncthreads();
  for (int j = threadIdx.y; j < 32; j += 8)
    out[(size_t)(c0 + j) * R + (r0 + threadIdx.x)] = tile[threadIdx.x][j];
}

// ---------- prior: sigmoid(hidden @ prior_w + b), renormalized over heads ----------
__global__ __launch_bounds__(256) void k_prior(const float* __restrict__ hidden,
                                               const float* __restrict__ pw,
                                               const float* __restrict__ pb,
                                               float* __restrict__ prior) {
  const int wid = threadIdx.x >> 6, lane = threadIdx.x & 63;
  const int t = blockIdx.x * 4 + wid;
  float acc[NHEAD] = {0.f, 0.f, 0.f, 0.f, 0.f, 0.f, 0.f, 0.f};
  const float* hrow = hidden + (size_t)t * H_DIM;
  for (int k = lane; k < H_DIM; k += 64) {
    float x = hrow[k];
    const float* wr = pw + k * NHEAD;
#pragma unroll
    for (int h = 0; h < NHEAD; ++h) acc[h] += x * wr[h];
  }
#pragma unroll
  for (int h = 0; h < NHEAD; ++h) {
#pragma unroll
    for (int off = 32; off >= 1; off >>= 1) acc[h] += __shfl_xor(acc[h], off);
  }
  if (lane == 0) {
    float p[NHEAD], s = 0.f;
#pragma unroll
    for (int h = 0; h < NHEAD; ++h) {
      p[h] = 1.f / (1.f + __expf(-(acc[h] + pb[h])));
      s += p[h];
    }
    float inv = 1.f / (s + 1e-8f);
#pragma unroll
    for (int h = 0; h < NHEAD; ++h) prior[t * NHEAD + h] = p[h] * inv;
  }
}

// ---------- m97-style GEMM: C[M,N] = epi(A[M,K] * Bt[N,K]^T + bias[N]) ----------
// 128x128 tile, BK=32, 4 waves (2x2), 16x16x32 f16 MFMA, global_load_lds staging,
// k-slot XOR swizzle (slot ^= (row>>1)&3) -> max 2-way LDS bank aliasing (free).
template <int TANH>
__global__ __launch_bounds__(256) void k_gemm(const f16* __restrict__ A,
                                              const f16* __restrict__ Bt,
                                              const float* __restrict__ bias,
                                              f16* __restrict__ C,
                                              int M, int N, int K) {
  __shared__ __align__(16) f16 sA[128 * 32];
  __shared__ __align__(16) f16 sB[128 * 32];
  const int tid = threadIdx.x;
  const int lane = tid & 63, wid = tid >> 6;
  const int wr = wid >> 1, wc = wid & 1;
  const int m0 = blockIdx.y * 128, n0 = blockIdx.x * 128;

  // staging: thread covers global (row = tid>>2 [+64], k-slot swizzled)
  const int rA = tid >> 2;
  const int swz = (((tid & 3) ^ ((tid >> 3) & 3))) * 8;  // element offset in [0,32)
  const f16* pA0 = A + (size_t)(m0 + rA) * K + swz;
  const f16* pA1 = pA0 + (size_t)64 * K;
  const f16* pB0 = Bt + (size_t)(n0 + rA) * K + swz;
  const f16* pB1 = pB0 + (size_t)64 * K;
  f16* lA0 = sA + wid * 512;        // 1KB per wave per instr, linear dest
  f16* lA1 = sA + (4 + wid) * 512;
  f16* lB0 = sB + wid * 512;
  f16* lB1 = sB + (4 + wid) * 512;

  f32x4 acc[4][4] = {};

  const int rr = lane & 15;
  const int ksw = (((lane >> 4) ^ ((rr >> 1) & 3))) * 8;  // swizzled read slot
  const int aoff = (wr * 64 + rr) * 32 + ksw;
  const int boff = (wc * 64 + rr) * 32 + ksw;

  for (int kt = 0; kt < K; kt += 32) {
    gload16(pA0 + kt, lA0);
    gload16(pA1 + kt, lA1);
    gload16(pB0 + kt, lB0);
    gload16(pB1 + kt, lB1);
    __syncthreads();  // vmcnt(0) drain + barrier: LDS tile ready
    f16x8 af[4], bf[4];
#pragma unroll
    for (int m = 0; m < 4; m++) af[m] = *(const f16x8*)&sA[aoff + m * 16 * 32];
#pragma unroll
    for (int n = 0; n < 4; n++) bf[n] = *(const f16x8*)&sB[boff + n * 16 * 32];
#pragma unroll
    for (int m = 0; m < 4; m++) {
#pragma unroll
      for (int n = 0; n < 4; n++)
        acc[m][n] = __builtin_amdgcn_mfma_f32_16x16x32_f16(af[m], bf[n], acc[m][n], 0, 0, 0);
    }
    __syncthreads();  // all reads done before next stage overwrites
  }

  // epilogue: D col = lane&15, row = (lane>>4)*4 + reg  [m89/m91 layout]
  const int crow = m0 + wr * 64 + ((lane >> 4) << 2);
  const int ccol0 = n0 + wc * 64 + rr;
#pragma unroll
  for (int n = 0; n < 4; n++) {
    const int col = ccol0 + n * 16;
    const float bv = bias[col];
#pragma unroll
    for (int m = 0; m < 4; m++) {
#pragma unroll
      for (int r = 0; r < 4; r++) {
        float v = acc[m][n][r] + bv;
        if (TANH) v = fast_tanh(v);
        C[(size_t)(crow + m * 16 + r) * N + col] = (f16)v;
      }
    }
  }
}

// ---------- per-token softmax over V per head + prior-weighted combine ----------
__global__ __launch_bounds__(256) void k_softmax(const f16* __restrict__ logits,
                                                 const float* __restrict__ prior,
                                                 float* __restrict__ out) {
  __shared__ float red[4];
  const int t = blockIdx.x;
  const int tid = threadIdx.x, lane = tid & 63, wid = tid >> 6;
  float oa[8] = {0.f, 0.f, 0.f, 0.f, 0.f, 0.f, 0.f, 0.f};
  const int v0 = tid * 8;
#pragma unroll 1
  for (int h = 0; h < NHEAD; ++h) {
    f16x8 x = *(const f16x8*)(logits + ((size_t)t * NHEAD + h) * V_DIM + v0);
    float xv[8], mx = -1e30f;
#pragma unroll
    for (int j = 0; j < 8; j++) { xv[j] = (float)x[j]; mx = fmaxf(mx, xv[j]); }
#pragma unroll
    for (int off = 32; off >= 1; off >>= 1) mx = fmaxf(mx, __shfl_xor(mx, off));
    if (lane == 0) red[wid] = mx;
    __syncthreads();
    mx = fmaxf(fmaxf(red[0], red[1]), fmaxf(red[2], red[3]));
    __syncthreads();
    float e[8], s = 0.f;
#pragma unroll
    for (int j = 0; j < 8; j++) { e[j] = __expf(xv[j] - mx); s += e[j]; }
#pragma unroll
    for (int off = 32; off >= 1; off >>= 1) s += __shfl_xor(s, off);
    if (lane == 0) red[wid] = s;
    __syncthreads();
    s = red[0] + red[1] + red[2] + red[3];
    __syncthreads();
    const float coef = prior[t * NHEAD + h] / s;
#pragma unroll
    for (int j = 0; j < 8; j++) oa[j] += coef * e[j];
  }
  float4* op = (float4*)(out + (size_t)t * V_DIM + v0);
  op[0] = make_float4(oa[0], oa[1], oa[2], oa[3]);
  op[1] = make_float4(oa[4], oa[5], oa[6], oa[7]);
}

extern "C" void kernel_launch(void* const* d_in, const int* in_sizes, int n_in,
                              void* d_out, int out_size, void* d_ws, size_t ws_size,
                              hipStream_t stream) {
  const float* hidden   = (const float*)d_in[0];
  const float* prior_w  = (const float*)d_in[1];
  const float* prior_b  = (const float*)d_in[2];
  const float* latent_w = (const float*)d_in[3];
  const float* latent_b = (const float*)d_in[4];
  const float* output_w = (const float*)d_in[5];
  const float* output_b = (const float*)d_in[6];
  float* out = (float*)d_out;

  char* ws = (char*)d_ws;
  size_t off = 0;
  auto alloc = [&](size_t bytes) -> void* {
    void* p = ws + off;
    off += (bytes + 255) & ~(size_t)255;
    return p;
  };
  f16* hidden_h = (f16*)alloc((size_t)T_TOK * H_DIM * 2);          // [8192][1024]
  f16* lw_t     = (f16*)alloc((size_t)NHEAD * H_DIM * H_DIM * 2);  // [8192][1024]
  f16* ow_t     = (f16*)alloc((size_t)V_DIM * H_DIM * 2);          // [2048][1024]
  float* prior  = (float*)alloc((size_t)T_TOK * NHEAD * 4);

  // choose token-chunk so ws fits (138.7MB at tc=2048)
  int tc = 2048;
  while (tc > 128) {
    size_t need = off + (size_t)tc * NHEAD * H_DIM * 2 + 256 +
                  (size_t)tc * NHEAD * V_DIM * 2 + 256;
    if (need <= ws_size) break;
    tc >>= 1;
  }
  f16* latent_h = (f16*)alloc((size_t)tc * NHEAD * H_DIM * 2);  // [tc*8][1024]
  f16* logits_h = (f16*)alloc((size_t)tc * NHEAD * V_DIM * 2);  // [tc*8][2048]

  // prep passes
  k_convert<<<(T_TOK * H_DIM / 4 + 255) / 256, 256, 0, stream>>>(
      hidden, hidden_h, T_TOK * H_DIM / 4);
  k_transpose<<<dim3(NHEAD * H_DIM / 32, H_DIM / 32), dim3(32, 8), 0, stream>>>(
      latent_w, lw_t, H_DIM, NHEAD * H_DIM);
  k_transpose<<<dim3(V_DIM / 32, H_DIM / 32), dim3(32, 8), 0, stream>>>(
      output_w, ow_t, H_DIM, V_DIM);
  k_prior<<<T_TOK / 4, 256, 0, stream>>>(hidden, prior_w, prior_b, prior);

  const int nchunk = T_TOK / tc;
  for (int c = 0; c < nchunk; ++c) {
    const f16* Ah = hidden_h + (size_t)c * tc * H_DIM;
    // latent = tanh(hidden @ latent_w + latent_b), stored [tc*8][1024] f16
    k_gemm<1><<<dim3(NHEAD * H_DIM / 128, tc / 128), 256, 0, stream>>>(
        Ah, lw_t, latent_b, latent_h, tc, NHEAD * H_DIM, H_DIM);
    // logits = latent @ output_w + output_b, stored [tc*8][2048] f16
    k_gemm<0><<<dim3(V_DIM / 128, tc * NHEAD / 128), 256, 0, stream>>>(
        latent_h, ow_t, output_b, logits_h, tc * NHEAD, V_DIM, H_DIM);
    // softmax over V per head, prior-weighted sum over heads
    k_softmax<<<tc, 256, 0, stream>>>(logits_h, prior + (size_t)c * tc * NHEAD,
                                      out + (size_t)c * tc * V_DIM);
  }
}

// Round 2
// 625.533 us; speedup vs baseline: 1.2315x; 1.2315x over previous
//
#include <hip/hip_runtime.h>
#include <hip/hip_bf16.h>
#include <stdint.h>

typedef _Float16 f16;
typedef _Float16 f16x8 __attribute__((ext_vector_type(8)));
typedef _Float16 f16x4 __attribute__((ext_vector_type(4)));
typedef float f32x4 __attribute__((ext_vector_type(4)));

#define T_TOK 8192
#define H_DIM 1024
#define NHEAD 8
#define V_DIM 2048

// global -> LDS direct load, 16B per lane. LDS dest = wave-uniform base + lane*16.
__device__ __forceinline__ void gload16(const void* g, void* l) {
  __builtin_amdgcn_global_load_lds(
      (const __attribute__((address_space(1))) void*)(uintptr_t)g,
      (__attribute__((address_space(3))) void*)(unsigned)(uintptr_t)l,
      16, 0, 0);
}

__device__ __forceinline__ float fast_tanh(float x) {
  float xc = fminf(fmaxf(x, -12.f), 12.f);
  float e = __expf(2.f * xc);
  return (e - 1.f) / (e + 1.f);
}

// Stage one half-tile (128 rows x 64 f16 = 16KB) with 2 global_load_lds.
// gRowBase = matrix ptr already offset to (rowbase, kt).
// Swizzle: global source col chunk = (tid&7) ^ (row&7)  (involution; read side
// applies the same XOR) so LDS dest stays linear per lane.
__device__ __forceinline__ void stage_half(const f16* __restrict__ gRowBase,
                                           char* ldsHalf, int tid, int sl8,
                                           int Kd) {
  const int srow = tid >> 3;
  char* wuni = ldsHalf + ((tid >> 6) << 10);  // wave-uniform base
  gload16(gRowBase + (size_t)srow * Kd + sl8, wuni);
  gload16(gRowBase + (size_t)(srow + 64) * Kd + sl8, wuni + 8192);
}

// ---------- 256x256x64 8-phase GEMM: C[M,N] = epi(A[M,K] * Bt[N,K]^T + bias)
// 8 waves (2M x 4N), per-wave 128x64 output = acc[8][4] f32x4.
// LDS 128KB: A,B each [2 buf][256][64] f16, XOR k-slot swizzle.
// Phase q: ds_read A m-pair {2q,2q+1} (+ all B at q0) | stage 1 half-tile |
//          barrier | lgkm0 | setprio1 | 16 MFMA | setprio0 | [q3: vmcnt(4)] | barrier
template <int TANH>
__global__ __launch_bounds__(512, 2) void k_gemm(const f16* __restrict__ A,
                                                 const f16* __restrict__ Bt,
                                                 const float* __restrict__ bias,
                                                 f16* __restrict__ C,
                                                 int M, int N, int K) {
  __shared__ __align__(16) f16 sA[2][16384];
  __shared__ __align__(16) f16 sB[2][16384];
  const int tid = threadIdx.x;
  const int lane = tid & 63;
  const int wid = tid >> 6;
  const int wr = wid >> 2, wc = wid & 3;
  const int m0 = blockIdx.y * 256, n0 = blockIdx.x * 256;
  const int NT = K >> 6;
  const int sl8 = ((tid & 7) ^ ((tid >> 3) & 7)) << 3;  // staging src col (f16)
  const int lo15 = lane & 15;
  // ds_read byte offsets within a 128-row panel, kh = 0/1 (k 0..31 / 32..63)
  const int offk0 = lo15 * 128 + (((lane >> 4)) ^ (lane & 7)) * 16;
  const int offk1 = lo15 * 128 + ((4 + (lane >> 4)) ^ (lane & 7)) * 16;

  const f16* Ag = A + (size_t)m0 * K;
  const f16* Bg = Bt + (size_t)n0 * K;
  char* sAb = (char*)&sA[0][0];
  char* sBb = (char*)&sB[0][0];

  // prologue: tile0 A+B -> buf0 (8 loads), tile1 B -> buf1 (4 loads)
  stage_half(Ag, sAb, tid, sl8, K);
  stage_half(Ag + (size_t)128 * K, sAb + 16384, tid, sl8, K);
  stage_half(Bg, sBb, tid, sl8, K);
  stage_half(Bg + (size_t)128 * K, sBb + 16384, tid, sl8, K);
  stage_half(Bg + 64, sBb + 32768, tid, sl8, K);
  stage_half(Bg + (size_t)128 * K + 64, sBb + 32768 + 16384, tid, sl8, K);
  asm volatile("s_waitcnt vmcnt(4)" ::: "memory");  // tile0 resident
  __builtin_amdgcn_s_barrier();
  __builtin_amdgcn_sched_barrier(0);

  f32x4 acc[8][4] = {};
  f16x8 bf[4][2];

#define PHASE(q, STAGE_STMT)                                                   \
  {                                                                            \
    f16x8 af[2];                                                               \
    f16x8 af1[2];                                                              \
    if (q == 0) {                                                              \
      _Pragma("unroll") for (int ni = 0; ni < 4; ++ni) {                       \
        bf[ni][0] = *(const f16x8*)(cB + wc * 8192 + ni * 2048 + offk0);       \
        bf[ni][1] = *(const f16x8*)(cB + wc * 8192 + ni * 2048 + offk1);       \
      }                                                                        \
    }                                                                          \
    af[0] = *(const f16x8*)(cA + wr * 16384 + (2 * q + 0) * 2048 + offk0);     \
    af[1] = *(const f16x8*)(cA + wr * 16384 + (2 * q + 0) * 2048 + offk1);     \
    af1[0] = *(const f16x8*)(cA + wr * 16384 + (2 * q + 1) * 2048 + offk0);    \
    af1[1] = *(const f16x8*)(cA + wr * 16384 + (2 * q + 1) * 2048 + offk1);    \
    STAGE_STMT;                                                                \
    __builtin_amdgcn_s_barrier();                                              \
    asm volatile("s_waitcnt lgkmcnt(0)" ::: "memory");                         \
    __builtin_amdgcn_sched_barrier(0);                                         \
    __builtin_amdgcn_s_setprio(1);                                             \
    _Pragma("unroll") for (int ni = 0; ni < 4; ++ni) {                         \
      acc[2 * q + 0][ni] = __builtin_amdgcn_mfma_f32_16x16x32_f16(             \
          af[0], bf[ni][0], acc[2 * q + 0][ni], 0, 0, 0);                      \
      acc[2 * q + 0][ni] = __builtin_amdgcn_mfma_f32_16x16x32_f16(             \
          af[1], bf[ni][1], acc[2 * q + 0][ni], 0, 0, 0);                      \
      acc[2 * q + 1][ni] = __builtin_amdgcn_mfma_f32_16x16x32_f16(             \
          af1[0], bf[ni][0], acc[2 * q + 1][ni], 0, 0, 0);                     \
      acc[2 * q + 1][ni] = __builtin_amdgcn_mfma_f32_16x16x32_f16(             \
          af1[1], bf[ni][1], acc[2 * q + 1][ni], 0, 0, 0);                     \
    }                                                                          \
    __builtin_amdgcn_s_setprio(0);                                             \
  }

#pragma unroll 2
  for (int T = 0; T < NT; ++T) {
    const int buf = T & 1;
    const char* cA = sAb + buf * 32768;
    const char* cB = sBb + buf * 32768;
    char* nA = sAb + (buf ^ 1) * 32768;  // A dest for tile T+1
    char* nB = sBb + buf * 32768;        // B dest for tile T+2 (same buf; B read
                                         // only in phase 0, sealed by its barrier)
    const int ktA = (T + 1) << 6;
    const int ktB = (T + 2) << 6;

    PHASE(0, { if (T + 1 < NT) stage_half(Ag + ktA, nA, tid, sl8, K); })
    __builtin_amdgcn_s_barrier();
    PHASE(1, { if (T + 1 < NT) stage_half(Ag + (size_t)128 * K + ktA, nA + 16384, tid, sl8, K); })
    __builtin_amdgcn_s_barrier();
    PHASE(2, { if (T + 2 < NT) stage_half(Bg + ktB, nB, tid, sl8, K); })
    __builtin_amdgcn_s_barrier();
    PHASE(3, { if (T + 2 < NT) stage_half(Bg + (size_t)128 * K + ktB, nB + 16384, tid, sl8, K); })
    if (T + 2 < NT) {
      asm volatile("s_waitcnt vmcnt(4)" ::: "memory");  // tile T+1 resident; B(T+2) in flight
    } else {
      asm volatile("s_waitcnt vmcnt(0)" ::: "memory");  // tail drain
    }
    __builtin_amdgcn_s_barrier();
    __builtin_amdgcn_sched_barrier(0);
  }
#undef PHASE

  // epilogue: D col = lane&15, row = (lane>>4)*4 + reg
  const int crow = m0 + wr * 128 + ((lane >> 4) << 2);
  const int ccol0 = n0 + wc * 64 + lo15;
#pragma unroll
  for (int ni = 0; ni < 4; ++ni) {
    const int col = ccol0 + ni * 16;
    const float bv = bias[col];
#pragma unroll
    for (int mi = 0; mi < 8; ++mi) {
#pragma unroll
      for (int r = 0; r < 4; ++r) {
        float v = acc[mi][ni][r] + bv;
        if (TANH) v = fast_tanh(v);
        C[(size_t)(crow + mi * 16 + r) * N + col] = (f16)v;
      }
    }
  }
}

// ---------- fp32 -> fp16 elementwise convert ----------
__global__ __launch_bounds__(256) void k_convert(const float* __restrict__ in,
                                                 f16* __restrict__ out, int n4) {
  int i = blockIdx.x * blockDim.x + threadIdx.x;
  if (i >= n4) return;
  const float4 v = ((const float4*)in)[i];
  f16x4 o;
  o[0] = (f16)v.x; o[1] = (f16)v.y; o[2] = (f16)v.z; o[3] = (f16)v.w;
  ((f16x4*)out)[i] = o;
}

// ---------- fp32 [R][C] -> fp16 [C][R] transpose-convert ----------
__global__ void k_transpose(const float* __restrict__ in, f16* __restrict__ out,
                            int R, int C) {
  __shared__ f16 tile[32][33];
  int c0 = blockIdx.x * 32, r0 = blockIdx.y * 32;
  for (int j = threadIdx.y; j < 32; j += 8)
    tile[j][threadIdx.x] = (f16)in[(size_t)(r0 + j) * C + (c0 + threadIdx.x)];
  __syncthreads();
  for (int j = threadIdx.y; j < 32; j += 8)
    out[(size_t)(c0 + j) * R + (r0 + threadIdx.x)] = tile[threadIdx.x][j];
}

// ---------- prior: sigmoid(hidden @ prior_w + b), renormalized over heads ----------
__global__ __launch_bounds__(256) void k_prior(const float* __restrict__ hidden,
                                               const float* __restrict__ pw,
                                               const float* __restrict__ pb,
                                               float* __restrict__ prior) {
  const int wid = threadIdx.x >> 6, lane = threadIdx.x & 63;
  const int t = blockIdx.x * 4 + wid;
  float acc[NHEAD] = {0.f, 0.f, 0.f, 0.f, 0.f, 0.f, 0.f, 0.f};
  const float* hrow = hidden + (size_t)t * H_DIM;
  for (int k = lane; k < H_DIM; k += 64) {
    float x = hrow[k];
    const float* wr = pw + k * NHEAD;
#pragma unroll
    for (int h = 0; h < NHEAD; ++h) acc[h] += x * wr[h];
  }
#pragma unroll
  for (int h = 0; h < NHEAD; ++h) {
#pragma unroll
    for (int off = 32; off >= 1; off >>= 1) acc[h] += __shfl_xor(acc[h], off);
  }
  if (lane == 0) {
    float p[NHEAD], s = 0.f;
#pragma unroll
    for (int h = 0; h < NHEAD; ++h) {
      p[h] = 1.f / (1.f + __expf(-(acc[h] + pb[h])));
      s += p[h];
    }
    float inv = 1.f / (s + 1e-8f);
#pragma unroll
    for (int h = 0; h < NHEAD; ++h) prior[t * NHEAD + h] = p[h] * inv;
  }
}

// ---------- per-token softmax over V per head + prior-weighted combine ----------
__global__ __launch_bounds__(256) void k_softmax(const f16* __restrict__ logits,
                                                 const float* __restrict__ prior,
                                                 float* __restrict__ out) {
  __shared__ float red[4];
  const int t = blockIdx.x;
  const int tid = threadIdx.x, lane = tid & 63, wid = tid >> 6;
  float oa[8] = {0.f, 0.f, 0.f, 0.f, 0.f, 0.f, 0.f, 0.f};
  const int v0 = tid * 8;
#pragma unroll 1
  for (int h = 0; h < NHEAD; ++h) {
    f16x8 x = *(const f16x8*)(logits + ((size_t)t * NHEAD + h) * V_DIM + v0);
    float xv[8], mx = -1e30f;
#pragma unroll
    for (int j = 0; j < 8; j++) { xv[j] = (float)x[j]; mx = fmaxf(mx, xv[j]); }
#pragma unroll
    for (int off = 32; off >= 1; off >>= 1) mx = fmaxf(mx, __shfl_xor(mx, off));
    if (lane == 0) red[wid] = mx;
    __syncthreads();
    mx = fmaxf(fmaxf(red[0], red[1]), fmaxf(red[2], red[3]));
    __syncthreads();
    float e[8], s = 0.f;
#pragma unroll
    for (int j = 0; j < 8; j++) { e[j] = __expf(xv[j] - mx); s += e[j]; }
#pragma unroll
    for (int off = 32; off >= 1; off >>= 1) s += __shfl_xor(s, off);
    if (lane == 0) red[wid] = s;
    __syncthreads();
    s = red[0] + red[1] + red[2] + red[3];
    __syncthreads();
    const float coef = prior[t * NHEAD + h] / s;
#pragma unroll
    for (int j = 0; j < 8; j++) oa[j] += coef * e[j];
  }
  float4* op = (float4*)(out + (size_t)t * V_DIM + v0);
  op[0] = make_float4(oa[0], oa[1], oa[2], oa[3]);
  op[1] = make_float4(oa[4], oa[5], oa[6], oa[7]);
}

extern "C" void kernel_launch(void* const* d_in, const int* in_sizes, int n_in,
                              void* d_out, int out_size, void* d_ws, size_t ws_size,
                              hipStream_t stream) {
  const float* hidden   = (const float*)d_in[0];
  const float* prior_w  = (const float*)d_in[1];
  const float* prior_b  = (const float*)d_in[2];
  const float* latent_w = (const float*)d_in[3];
  const float* latent_b = (const float*)d_in[4];
  const float* output_w = (const float*)d_in[5];
  const float* output_b = (const float*)d_in[6];
  float* out = (float*)d_out;

  char* ws = (char*)d_ws;
  size_t off = 0;
  auto alloc = [&](size_t bytes) -> void* {
    void* p = ws + off;
    off += (bytes + 255) & ~(size_t)255;
    return p;
  };
  f16* hidden_h = (f16*)alloc((size_t)T_TOK * H_DIM * 2);          // [8192][1024]
  f16* lw_t     = (f16*)alloc((size_t)NHEAD * H_DIM * H_DIM * 2);  // [8192][1024]
  f16* ow_t     = (f16*)alloc((size_t)V_DIM * H_DIM * 2);          // [2048][1024]
  float* prior  = (float*)alloc((size_t)T_TOK * NHEAD * 4);

  // token-chunk sized to fit ws (138.7MB at tc=2048); must stay multiple of 256
  int tc = 2048;
  while (tc > 256) {
    size_t need = off + (size_t)tc * NHEAD * H_DIM * 2 + 256 +
                  (size_t)tc * NHEAD * V_DIM * 2 + 256;
    if (need <= ws_size) break;
    tc >>= 1;
  }
  f16* latent_h = (f16*)alloc((size_t)tc * NHEAD * H_DIM * 2);  // [tc*8][1024]
  f16* logits_h = (f16*)alloc((size_t)tc * NHEAD * V_DIM * 2);  // [tc*8][2048]

  // prep passes
  k_convert<<<(T_TOK * H_DIM / 4 + 255) / 256, 256, 0, stream>>>(
      hidden, hidden_h, T_TOK * H_DIM / 4);
  k_transpose<<<dim3(NHEAD * H_DIM / 32, H_DIM / 32), dim3(32, 8), 0, stream>>>(
      latent_w, lw_t, H_DIM, NHEAD * H_DIM);
  k_transpose<<<dim3(V_DIM / 32, H_DIM / 32), dim3(32, 8), 0, stream>>>(
      output_w, ow_t, H_DIM, V_DIM);
  k_prior<<<T_TOK / 4, 256, 0, stream>>>(hidden, prior_w, prior_b, prior);

  const int nchunk = T_TOK / tc;
  for (int c = 0; c < nchunk; ++c) {
    const f16* Ah = hidden_h + (size_t)c * tc * H_DIM;
    // latent = tanh(hidden @ latent_w + latent_b), stored [tc*8][1024] f16
    k_gemm<1><<<dim3(NHEAD * H_DIM / 256, tc / 256), 512, 0, stream>>>(
        Ah, lw_t, latent_b, latent_h, tc, NHEAD * H_DIM, H_DIM);
    // logits = latent @ output_w + output_b, stored [tc*8][2048] f16
    k_gemm<0><<<dim3(V_DIM / 256, tc * NHEAD / 256), 512, 0, stream>>>(
        latent_h, ow_t, output_b, logits_h, tc * NHEAD, V_DIM, H_DIM);
    // softmax over V per head, prior-weighted sum over heads
    k_softmax<<<tc, 256, 0, stream>>>(logits_h, prior + (size_t)c * tc * NHEAD,
                                      out + (size_t)c * tc * V_DIM);
  }
}

// Round 3
// 582.995 us; speedup vs baseline: 1.3214x; 1.0730x over previous
//
#include <hip/hip_runtime.h>
#include <hip/hip_bf16.h>
#include <stdint.h>

typedef _Float16 f16;
typedef _Float16 f16x8 __attribute__((ext_vector_type(8)));
typedef _Float16 f16x4 __attribute__((ext_vector_type(4)));
typedef float f32x4 __attribute__((ext_vector_type(4)));

#define T_TOK 8192
#define H_DIM 1024
#define NHEAD 8
#define V_DIM 2048

// global -> LDS direct load, 16B per lane. LDS dest = wave-uniform base + lane*16.
__device__ __forceinline__ void gload16(const void* g, void* l) {
  __builtin_amdgcn_global_load_lds(
      (const __attribute__((address_space(1))) void*)(uintptr_t)g,
      (__attribute__((address_space(3))) void*)(unsigned)(uintptr_t)l,
      16, 0, 0);
}

__device__ __forceinline__ float fast_tanh(float x) {
  float xc = fminf(fmaxf(x, -12.f), 12.f);
  float e = __expf(2.f * xc);
  return (e - 1.f) / (e + 1.f);
}

// Stage one half-tile (128 rows x 64 f16 = 16KB) with 2 global_load_lds.
__device__ __forceinline__ void stage_half(const f16* __restrict__ gRowBase,
                                           char* ldsHalf, int tid, int sl8,
                                           int Kd) {
  const int srow = tid >> 3;
  char* wuni = ldsHalf + ((tid >> 6) << 10);  // wave-uniform base
  gload16(gRowBase + (size_t)srow * Kd + sl8, wuni);
  gload16(gRowBase + (size_t)(srow + 64) * Kd + sl8, wuni + 8192);
}

// ---------- 256x256x64 pipelined 4-phase GEMM: C = epi(A[M,K]*Bt[N,K]^T + bias)
// 8 waves (2M x 4N), per-wave 128x64 out = acc[8][4] f32x4 (AGPR).
// af ping-pong: phase q's fragments loaded during phase q-1 (overlap LDS/MFMA).
// 1 raw barrier per phase; counted vmcnt(4) once per K-tile (T4); setprio (T5).
template <int TANH>
__global__ __launch_bounds__(512, 2) void k_gemm(const f16* __restrict__ A,
                                                 const f16* __restrict__ Bt,
                                                 const float* __restrict__ bias,
                                                 f16* __restrict__ C,
                                                 int M, int N, int K) {
  __shared__ __align__(16) f16 sA[2][16384];
  __shared__ __align__(16) f16 sB[2][16384];
  const int tid = threadIdx.x;
  const int lane = tid & 63;
  const int wid = tid >> 6;
  const int wr = wid >> 2, wc = wid & 3;
  // XCD-aware block swizzle (T1); all grids are multiples of 8 blocks
  const int gx = gridDim.x;
  const int id = blockIdx.y * gx + blockIdx.x;
  const int cpx = (gx * gridDim.y) >> 3;
  const int sw = (id & 7) * cpx + (id >> 3);
  const int m0 = (sw / gx) * 256, n0 = (sw % gx) * 256;
  const int NT = K >> 6;  // NT even (K % 128 == 0)
  const int sl8 = ((tid & 7) ^ ((tid >> 3) & 7)) << 3;  // staging src col (f16)
  const int lo15 = lane & 15;
  const int offk0 = lo15 * 128 + (((lane >> 4)) ^ (lane & 7)) * 16;
  const int offk1 = lo15 * 128 + ((4 + (lane >> 4)) ^ (lane & 7)) * 16;

  const f16* Ag = A + (size_t)m0 * K;
  const f16* Bg = Bt + (size_t)n0 * K;
  char* sAb = (char*)&sA[0][0];
  char* sBb = (char*)&sB[0][0];

  // prologue: tile0 A+B -> buf0, tile1 B -> buf1
  stage_half(Ag, sAb, tid, sl8, K);
  stage_half(Ag + (size_t)128 * K, sAb + 16384, tid, sl8, K);
  stage_half(Bg, sBb, tid, sl8, K);
  stage_half(Bg + (size_t)128 * K, sBb + 16384, tid, sl8, K);
  stage_half(Bg + 64, sBb + 32768, tid, sl8, K);
  stage_half(Bg + (size_t)128 * K + 64, sBb + 32768 + 16384, tid, sl8, K);
  asm volatile("s_waitcnt vmcnt(4)" ::: "memory");  // tile0 A+B resident
  __builtin_amdgcn_s_barrier();
  __builtin_amdgcn_sched_barrier(0);

  f32x4 acc[8][4] = {};
  f16x8 af0[4], af1[4], bf[4][2];

#define LDA_SET(dst, base, q)                                                  \
  {                                                                            \
    dst[0] = *(const f16x8*)((base) + wr * 16384 + (2 * (q) + 0) * 2048 + offk0); \
    dst[1] = *(const f16x8*)((base) + wr * 16384 + (2 * (q) + 0) * 2048 + offk1); \
    dst[2] = *(const f16x8*)((base) + wr * 16384 + (2 * (q) + 1) * 2048 + offk0); \
    dst[3] = *(const f16x8*)((base) + wr * 16384 + (2 * (q) + 1) * 2048 + offk1); \
  }
#define LDB(base)                                                              \
  {                                                                            \
    _Pragma("unroll") for (int ni = 0; ni < 4; ++ni) {                         \
      bf[ni][0] = *(const f16x8*)((base) + wc * 8192 + ni * 2048 + offk0);     \
      bf[ni][1] = *(const f16x8*)((base) + wc * 8192 + ni * 2048 + offk1);     \
    }                                                                          \
  }
#define MFMA16(q, S)                                                           \
  {                                                                            \
    __builtin_amdgcn_s_setprio(1);                                             \
    _Pragma("unroll") for (int ni = 0; ni < 4; ++ni) {                         \
      acc[2 * (q) + 0][ni] = __builtin_amdgcn_mfma_f32_16x16x32_f16(           \
          S[0], bf[ni][0], acc[2 * (q) + 0][ni], 0, 0, 0);                     \
      acc[2 * (q) + 0][ni] = __builtin_amdgcn_mfma_f32_16x16x32_f16(           \
          S[1], bf[ni][1], acc[2 * (q) + 0][ni], 0, 0, 0);                     \
      acc[2 * (q) + 1][ni] = __builtin_amdgcn_mfma_f32_16x16x32_f16(           \
          S[2], bf[ni][0], acc[2 * (q) + 1][ni], 0, 0, 0);                     \
      acc[2 * (q) + 1][ni] = __builtin_amdgcn_mfma_f32_16x16x32_f16(           \
          S[3], bf[ni][1], acc[2 * (q) + 1][ni], 0, 0, 0);                     \
    }                                                                          \
    __builtin_amdgcn_s_setprio(0);                                             \
  }

  // preload phase-0 fragments of tile 0
  LDA_SET(af0, sAb, 0);

#define HALF(tt, bc)                                                           \
  {                                                                            \
    const char* cA = sAb + (bc)*32768;                                         \
    const char* cB = sBb + (bc)*32768;                                         \
    char* nA = sAb + ((bc) ^ 1) * 32768;                                       \
    char* nB = sBb + (bc)*32768;                                               \
    const int ktA = ((tt) + 1) << 6, ktB = ((tt) + 2) << 6;                    \
    const bool doA = (tt) + 1 < NT, doB = (tt) + 2 < NT;                       \
    /* ph0: B regs + af(ph1) issue, MFMA ph0 */                                \
    if (doA) stage_half(Ag + ktA, nA, tid, sl8, K);                            \
    LDB(cB);                                                                   \
    LDA_SET(af1, cA, 1);                                                       \
    __builtin_amdgcn_sched_barrier(0);                                         \
    MFMA16(0, af0);                                                            \
    __builtin_amdgcn_s_barrier();                                              \
    /* ph1 */                                                                  \
    if (doA) stage_half(Ag + (size_t)128 * K + ktA, nA + 16384, tid, sl8, K);  \
    LDA_SET(af0, cA, 2);                                                       \
    __builtin_amdgcn_sched_barrier(0);                                         \
    MFMA16(1, af1);                                                            \
    __builtin_amdgcn_s_barrier();                                              \
    /* ph2 */                                                                  \
    if (doB) stage_half(Bg + ktB, nB, tid, sl8, K);                            \
    LDA_SET(af1, cA, 3);                                                       \
    __builtin_amdgcn_sched_barrier(0);                                         \
    MFMA16(2, af0);                                                            \
    __builtin_amdgcn_s_barrier();                                              \
    /* ph3: counted vmcnt; preload next tile ph0 after barrier */              \
    if (doB) stage_half(Bg + (size_t)128 * K + ktB, nB + 16384, tid, sl8, K);  \
    if (doB) {                                                                 \
      asm volatile("s_waitcnt vmcnt(4)" ::: "memory");                         \
    } else {                                                                   \
      asm volatile("s_waitcnt vmcnt(0)" ::: "memory");                         \
    }                                                                          \
    __builtin_amdgcn_s_barrier();                                              \
    __builtin_amdgcn_sched_barrier(0);                                         \
    if (doA) LDA_SET(af0, sAb + ((bc) ^ 1) * 32768, 0);                        \
    __builtin_amdgcn_sched_barrier(0);                                         \
    MFMA16(3, af1);                                                            \
  }

#pragma unroll 1
  for (int T = 0; T < NT; T += 2) {
    HALF(T, 0);
    HALF(T + 1, 1);
  }
#undef HALF
#undef LDA_SET
#undef LDB
#undef MFMA16

  // epilogue: D col = lane&15, row = (lane>>4)*4 + reg.
  // Loop order row-outer / ni-inner so the 4 stores hitting each 128B line are
  // consecutive -> L2 write-combining, no partial-line RMW.
  const int crow = m0 + wr * 128 + ((lane >> 4) << 2);
  const int ccol0 = n0 + wc * 64 + lo15;
  float bv[4];
#pragma unroll
  for (int ni = 0; ni < 4; ++ni) bv[ni] = bias[ccol0 + ni * 16];
#pragma unroll
  for (int mi = 0; mi < 8; ++mi) {
#pragma unroll
    for (int r = 0; r < 4; ++r) {
      f16* Crow = C + (size_t)(crow + mi * 16 + r) * N;
#pragma unroll
      for (int ni = 0; ni < 4; ++ni) {
        float v = acc[mi][ni][r] + bv[ni];
        if (TANH) v = fast_tanh(v);
        Crow[ccol0 + ni * 16] = (f16)v;
      }
    }
  }
}

// ---------- fp32 -> fp16 elementwise convert ----------
__global__ __launch_bounds__(256) void k_convert(const float* __restrict__ in,
                                                 f16* __restrict__ out, int n4) {
  int i = blockIdx.x * blockDim.x + threadIdx.x;
  if (i >= n4) return;
  const float4 v = ((const float4*)in)[i];
  f16x4 o;
  o[0] = (f16)v.x; o[1] = (f16)v.y; o[2] = (f16)v.z; o[3] = (f16)v.w;
  ((f16x4*)out)[i] = o;
}

// ---------- fp32 [R][C] -> fp16 [C][R] transpose-convert ----------
__global__ void k_transpose(const float* __restrict__ in, f16* __restrict__ out,
                            int R, int C) {
  __shared__ f16 tile[32][33];
  int c0 = blockIdx.x * 32, r0 = blockIdx.y * 32;
  for (int j = threadIdx.y; j < 32; j += 8)
    tile[j][threadIdx.x] = (f16)in[(size_t)(r0 + j) * C + (c0 + threadIdx.x)];
  __syncthreads();
  for (int j = threadIdx.y; j < 32; j += 8)
    out[(size_t)(c0 + j) * R + (r0 + threadIdx.x)] = tile[threadIdx.x][j];
}

// ---------- prior: sigmoid(hidden @ prior_w + b), renormalized over heads ----------
__global__ __launch_bounds__(256) void k_prior(const float* __restrict__ hidden,
                                               const float* __restrict__ pw,
                                               const float* __restrict__ pb,
                                               float* __restrict__ prior) {
  const int wid = threadIdx.x >> 6, lane = threadIdx.x & 63;
  const int t = blockIdx.x * 4 + wid;
  float acc[NHEAD] = {0.f, 0.f, 0.f, 0.f, 0.f, 0.f, 0.f, 0.f};
  const float* hrow = hidden + (size_t)t * H_DIM;
  for (int k = lane; k < H_DIM; k += 64) {
    float x = hrow[k];
    const float* wr = pw + k * NHEAD;
#pragma unroll
    for (int h = 0; h < NHEAD; ++h) acc[h] += x * wr[h];
  }
#pragma unroll
  for (int h = 0; h < NHEAD; ++h) {
#pragma unroll
    for (int off = 32; off >= 1; off >>= 1) acc[h] += __shfl_xor(acc[h], off);
  }
  if (lane == 0) {
    float p[NHEAD], s = 0.f;
#pragma unroll
    for (int h = 0; h < NHEAD; ++h) {
      p[h] = 1.f / (1.f + __expf(-(acc[h] + pb[h])));
      s += p[h];
    }
    float inv = 1.f / (s + 1e-8f);
#pragma unroll
    for (int h = 0; h < NHEAD; ++h) prior[t * NHEAD + h] = p[h] * inv;
  }
}

// ---------- per-token softmax over V per head + prior-weighted combine ----------
__global__ __launch_bounds__(256) void k_softmax(const f16* __restrict__ logits,
                                                 const float* __restrict__ prior,
                                                 float* __restrict__ out) {
  __shared__ float red[4];
  const int t = blockIdx.x;
  const int tid = threadIdx.x, lane = tid & 63, wid = tid >> 6;
  float oa[8] = {0.f, 0.f, 0.f, 0.f, 0.f, 0.f, 0.f, 0.f};
  const int v0 = tid * 8;
#pragma unroll 1
  for (int h = 0; h < NHEAD; ++h) {
    f16x8 x = *(const f16x8*)(logits + ((size_t)t * NHEAD + h) * V_DIM + v0);
    float xv[8], mx = -1e30f;
#pragma unroll
    for (int j = 0; j < 8; j++) { xv[j] = (float)x[j]; mx = fmaxf(mx, xv[j]); }
#pragma unroll
    for (int off = 32; off >= 1; off >>= 1) mx = fmaxf(mx, __shfl_xor(mx, off));
    if (lane == 0) red[wid] = mx;
    __syncthreads();
    mx = fmaxf(fmaxf(red[0], red[1]), fmaxf(red[2], red[3]));
    __syncthreads();
    float e[8], s = 0.f;
#pragma unroll
    for (int j = 0; j < 8; j++) { e[j] = __expf(xv[j] - mx); s += e[j]; }
#pragma unroll
    for (int off = 32; off >= 1; off >>= 1) s += __shfl_xor(s, off);
    if (lane == 0) red[wid] = s;
    __syncthreads();
    s = red[0] + red[1] + red[2] + red[3];
    __syncthreads();
    const float coef = prior[t * NHEAD + h] / s;
#pragma unroll
    for (int j = 0; j < 8; j++) oa[j] += coef * e[j];
  }
  float4* op = (float4*)(out + (size_t)t * V_DIM + v0);
  op[0] = make_float4(oa[0], oa[1], oa[2], oa[3]);
  op[1] = make_float4(oa[4], oa[5], oa[6], oa[7]);
}

extern "C" void kernel_launch(void* const* d_in, const int* in_sizes, int n_in,
                              void* d_out, int out_size, void* d_ws, size_t ws_size,
                              hipStream_t stream) {
  const float* hidden   = (const float*)d_in[0];
  const float* prior_w  = (const float*)d_in[1];
  const float* prior_b  = (const float*)d_in[2];
  const float* latent_w = (const float*)d_in[3];
  const float* latent_b = (const float*)d_in[4];
  const float* output_w = (const float*)d_in[5];
  const float* output_b = (const float*)d_in[6];
  float* out = (float*)d_out;

  char* ws = (char*)d_ws;
  size_t off = 0;
  auto alloc = [&](size_t bytes) -> void* {
    void* p = ws + off;
    off += (bytes + 255) & ~(size_t)255;
    return p;
  };
  f16* hidden_h = (f16*)alloc((size_t)T_TOK * H_DIM * 2);          // [8192][1024]
  f16* lw_t     = (f16*)alloc((size_t)NHEAD * H_DIM * H_DIM * 2);  // [8192][1024]
  f16* ow_t     = (f16*)alloc((size_t)V_DIM * H_DIM * 2);          // [2048][1024]
  float* prior  = (float*)alloc((size_t)T_TOK * NHEAD * 4);

  // token-chunk sized to fit ws (138.7MB at tc=2048); must stay multiple of 256
  int tc = 2048;
  while (tc > 256) {
    size_t need = off + (size_t)tc * NHEAD * H_DIM * 2 + 256 +
                  (size_t)tc * NHEAD * V_DIM * 2 + 256;
    if (need <= ws_size) break;
    tc >>= 1;
  }
  f16* latent_h = (f16*)alloc((size_t)tc * NHEAD * H_DIM * 2);  // [tc*8][1024]
  f16* logits_h = (f16*)alloc((size_t)tc * NHEAD * V_DIM * 2);  // [tc*8][2048]

  // prep passes
  k_convert<<<(T_TOK * H_DIM / 4 + 255) / 256, 256, 0, stream>>>(
      hidden, hidden_h, T_TOK * H_DIM / 4);
  k_transpose<<<dim3(NHEAD * H_DIM / 32, H_DIM / 32), dim3(32, 8), 0, stream>>>(
      latent_w, lw_t, H_DIM, NHEAD * H_DIM);
  k_transpose<<<dim3(V_DIM / 32, H_DIM / 32), dim3(32, 8), 0, stream>>>(
      output_w, ow_t, H_DIM, V_DIM);
  k_prior<<<T_TOK / 4, 256, 0, stream>>>(hidden, prior_w, prior_b, prior);

  const int nchunk = T_TOK / tc;
  for (int c = 0; c < nchunk; ++c) {
    const f16* Ah = hidden_h + (size_t)c * tc * H_DIM;
    // latent = tanh(hidden @ latent_w + latent_b), stored [tc*8][1024] f16
    k_gemm<1><<<dim3(NHEAD * H_DIM / 256, tc / 256), 512, 0, stream>>>(
        Ah, lw_t, latent_b, latent_h, tc, NHEAD * H_DIM, H_DIM);
    // logits = latent @ output_w + output_b, stored [tc*8][2048] f16
    k_gemm<0><<<dim3(V_DIM / 256, tc * NHEAD / 256), 512, 0, stream>>>(
        latent_h, ow_t, output_b, logits_h, tc * NHEAD, V_DIM, H_DIM);
    // softmax over V per head, prior-weighted sum over heads
    k_softmax<<<tc, 256, 0, stream>>>(logits_h, prior + (size_t)c * tc * NHEAD,
                                      out + (size_t)c * tc * V_DIM);
  }
}